// Round 1
// 2576.566 us; speedup vs baseline: 1.1884x; 1.1884x over previous
//
#include <hip/hip_runtime.h>

typedef unsigned int u32;
typedef unsigned short u16;
typedef short bf16x8 __attribute__((ext_vector_type(8)));
typedef u16 u16x8 __attribute__((ext_vector_type(8)));
typedef float f32x4 __attribute__((ext_vector_type(4)));
typedef _Float16 h2v __attribute__((ext_vector_type(2)));

#define HID 256
#define NCLS 64
#define GATES 1024
#define SEQ 512
#define NBATCH 256
#define FEAT 512
#define INDIM 576

// ---------- helpers ----------
__device__ __forceinline__ u16 f2b(float f) {              // fp32 -> bf16 RNE
  u32 u = __builtin_bit_cast(u32, f);
  u += 0x7fffu + ((u >> 16) & 1u);
  return (u16)(u >> 16);
}
__device__ __forceinline__ float b2f(u16 v) {
  u32 u = ((u32)v) << 16;
  return __builtin_bit_cast(float, u);
}
__device__ __forceinline__ u32 packh2(float a, float b) {  // two fp32 -> packed f16x2
  u16 lo = __builtin_bit_cast(u16, (_Float16)a);
  u16 hi = __builtin_bit_cast(u16, (_Float16)b);
  return (u32)lo | ((u32)hi << 16);
}
__device__ __forceinline__ float fdot2a(u32 h, u32 w, float c) {
#if __has_builtin(__builtin_amdgcn_fdot2)
  return __builtin_amdgcn_fdot2(__builtin_bit_cast(h2v, h),
                                __builtin_bit_cast(h2v, w), c, false);
#else
  h2v a = __builtin_bit_cast(h2v, h);
  h2v b = __builtin_bit_cast(h2v, w);
  return c + (float)a[0] * (float)b[0] + (float)a[1] * (float)b[1];
#endif
}
__device__ __forceinline__ float sigmf_(float x) { return 1.f / (1.f + __expf(-x)); }
__device__ __forceinline__ float tanhf_(float x) { return 1.f - 2.f / (1.f + __expf(2.f * x)); }

// ---------- kernel 0: weight prep + out zero ----------
// Wihk  : bf16 [1024][512]  x-part of W_ih (for GEMM), unchanged.
// WhhF  : u32  [48][512][4] register frags. Thread t: kq=t>>7, gl=t&127.
//         frag i=j*8+qq (j in [0,6), qq in [0,8)): component q holds pair
//         (W_hh[gl+j*128][kq*64+qq*8+2q], ...+1) as f16x2.
// WhhL2 : u32  [16][512][4] LDS frags, same formula with j in {6,7}, i2=(j-6)*8+qq.
// WoutR : u32  [16][512]    unchanged.
// Woh2  : f32  [64][256][4] Woh2[p][c][jj] = W_ih[(jj*256+c)*576 + 512+p]
//         (one float4 per cell thread, matches gate set {c,c+256,c+512,c+768}).
__global__ void prep_kernel(const float* __restrict__ W_ih, const float* __restrict__ W_hh,
                            const float* __restrict__ W_out,
                            u16* __restrict__ Wihk, u32* __restrict__ WhhF,
                            u32* __restrict__ WhhL2, u32* __restrict__ WoutR,
                            float* __restrict__ Woh2, float* __restrict__ out) {
  int idx = blockIdx.x * 256 + threadIdx.x;
  const int N0 = 1024 * 512;            // Wihk
  const int N1 = N0 + 48 * 512 * 4;     // WhhF (98304 u32, same bytes as before)
  const int N2 = N1 + 16 * 512 * 4;     // WhhL2 (32768 u32)
  const int N3 = N2 + 16 * 512;         // WoutR
  const int N4 = N3 + 64 * 256 * 4;     // Woh2 (65536 f32)
  if (idx < N0) {
    int g = idx >> 9, k = idx & 511;
    Wihk[idx] = f2b(W_ih[g * INDIM + k]);
  } else if (idx < N1) {
    int r = idx - N0;
    int q = r & 3, u4 = r >> 2;
    int t = u4 & 511, i = u4 >> 9;          // i in [0,48)
    int j = i >> 3, qq = i & 7;
    int kqv = t >> 7, glv = t & 127;
    int g = glv + j * 128;
    int k = kqv * 64 + qq * 8 + 2 * q;
    WhhF[r] = packh2(W_hh[g * HID + k], W_hh[g * HID + k + 1]);
  } else if (idx < N2) {
    int r = idx - N1;
    int q = r & 3, u4 = r >> 2;
    int t = u4 & 511, i2 = u4 >> 9;         // i2 in [0,16)
    int j = 6 + (i2 >> 3), qq = i2 & 7;
    int kqv = t >> 7, glv = t & 127;
    int g = glv + j * 128;
    int k = kqv * 64 + qq * 8 + 2 * q;
    WhhL2[r] = packh2(W_hh[g * HID + k], W_hh[g * HID + k + 1]);
  } else if (idx < N3) {
    int r = idx - N2;
    int j = r >> 9, t = r & 511;
    int cc = t & 63, kqv = t >> 6;
    int k0 = kqv * 32 + 2 * j;
    WoutR[r] = packh2(W_out[cc * HID + k0], W_out[cc * HID + k0 + 1]);
  } else if (idx < N4) {
    int r = idx - N3;
    int jj = r & 3, c = (r >> 2) & 255, p = r >> 10;
    Woh2[r] = W_ih[(jj * 256 + c) * INDIM + FEAT + p];
  } else if (idx == N4) {
    out[0] = 0.f;
  }
}

// ---------- kernel 1: Xp = bf16( x @ W_ih[:, :512]^T + b_ih + b_hh ) ----------
// Store permuted cell-major: gate col g stored at (g&255)*4 + (g>>8) so the
// recurrent kernel's cell thread c loads its 4 gates {c,c+256,c+512,c+768}
// as one ushort4.
__global__ __launch_bounds__(256) void gemm_xp(const float* __restrict__ x,
                                               const u16* __restrict__ Wihk,
                                               const float* __restrict__ b_ih,
                                               const float* __restrict__ b_hh,
                                               u16* __restrict__ Xp) {
  __shared__ u16 As[128 * 32];
  __shared__ u16 Bs[128 * 32];
  const int tid = threadIdx.x;
  const int bx = blockIdx.x;
  const int m0 = (bx >> 3) * 128;
  const int n0 = (bx & 7) * 128;
  const int wave = tid >> 6, lane = tid & 63;
  const int wm = (wave >> 1) * 64, wn = (wave & 1) * 64;
  const int l16 = lane & 15, quad = lane >> 4;
  const int r = tid >> 2;
  const int c8 = (tid & 3) * 8;

  f32x4 zero4 = {0.f, 0.f, 0.f, 0.f};
  f32x4 acc[4][4];
#pragma unroll
  for (int i = 0; i < 4; ++i)
#pragma unroll
    for (int j = 0; j < 4; ++j) acc[i][j] = zero4;

  for (int k0 = 0; k0 < FEAT; k0 += 32) {
#pragma unroll
    for (int p = 0; p < 2; ++p) {
      const float* src = x + (size_t)(m0 + r + p * 64) * FEAT + k0 + c8;
      float4 f0 = *(const float4*)src;
      float4 f1 = *(const float4*)(src + 4);
      u16x8 v;
      v[0] = f2b(f0.x); v[1] = f2b(f0.y); v[2] = f2b(f0.z); v[3] = f2b(f0.w);
      v[4] = f2b(f1.x); v[5] = f2b(f1.y); v[6] = f2b(f1.z); v[7] = f2b(f1.w);
      *(u16x8*)&As[(r + p * 64) * 32 + c8] = v;
    }
#pragma unroll
    for (int p = 0; p < 2; ++p) {
      *(uint4*)&Bs[(r + p * 64) * 32 + c8] =
          *(const uint4*)&Wihk[(size_t)(n0 + r + p * 64) * FEAT + k0 + c8];
    }
    __syncthreads();
    bf16x8 am[4], bn[4];
#pragma unroll
    for (int i = 0; i < 4; ++i)
      am[i] = *(const bf16x8*)&As[(wm + i * 16 + l16) * 32 + quad * 8];
#pragma unroll
    for (int j = 0; j < 4; ++j)
      bn[j] = *(const bf16x8*)&Bs[(wn + j * 16 + l16) * 32 + quad * 8];
#pragma unroll
    for (int i = 0; i < 4; ++i)
#pragma unroll
      for (int j = 0; j < 4; ++j)
        acc[i][j] = __builtin_amdgcn_mfma_f32_16x16x32_bf16(am[i], bn[j], acc[i][j], 0, 0, 0);
    __syncthreads();
  }

  float bias[4];
  int cols[4];
#pragma unroll
  for (int j = 0; j < 4; ++j) {
    cols[j] = n0 + wn + j * 16 + l16;
    bias[j] = b_ih[cols[j]] + b_hh[cols[j]];
  }
#pragma unroll
  for (int i = 0; i < 4; ++i) {
    int rowb = m0 + wm + i * 16 + quad * 4;
#pragma unroll
    for (int j = 0; j < 4; ++j) {
      int pcol = ((cols[j] & 255) << 2) + (cols[j] >> 8);
#pragma unroll
      for (int rr = 0; rr < 4; ++rr) {
        Xp[(size_t)(rowb + rr) * GATES + pcol] = f2b(acc[i][j][rr] + bias[j]);
      }
    }
  }
}

// ---------- kernel 2: persistent recurrent decoder ----------
// 256 blocks (1 batch row) x 512 threads. K-quarter split: thread t has
// kq = t>>7 (K range [kq*64, kq*64+64)) and 8 gates gl + j*128 (gl = t&127).
// Each h-frag ds_read feeds 32 fdot2 (vs 8 before) -> LDS latency self-hides.
// Partials reduced through LDS pA[kq*1024 + g] in phase B.
__global__ __launch_bounds__(512, 2) void lstm_seq(
    const u16* __restrict__ Xp, const uint4* __restrict__ WhhF,
    const uint4* __restrict__ WhhL2, const u32* __restrict__ WoutR,
    const float4* __restrict__ Woh2, const float* __restrict__ b_out,
    const int* __restrict__ tag, float* __restrict__ out) {
  extern __shared__ u32 smem[];
  uint4* whhl = (uint4*)smem;             // [0, 32768) u32 : 8192 uint4
  float* pA   = (float*)(smem + 32768);   // 4096 f32 : partials kq*1024 + g
  u32*  h_u32 = smem + 36864;             // 128 u32 (256 f16)
  float* pbuf = (float*)(smem + 36992);   // 512 f32 : logit partials
  int*  tag_l = (int*)(smem + 37504);     // 512 i32
  int*  predv = (int*)(smem + 38016);

  const int tid = threadIdx.x;
  const int b = blockIdx.x;
  const int kq = tid >> 7;   // K-quarter (wave-uniform)
  const int gl = tid & 127;

  // ---- init: weights into registers / LDS ----
  uint4 wr[48];   // frags j in [0,6): wr[j*8+qq]
#pragma unroll
  for (int i = 0; i < 48; ++i) wr[i] = WhhF[i * 512 + tid];
  u32 wo[16];
#pragma unroll
  for (int i = 0; i < 16; ++i) wo[i] = WoutR[i * 512 + tid];
#pragma unroll
  for (int i = 0; i < 16; ++i) whhl[i * 512 + tid] = WhhL2[i * 512 + tid];
  tag_l[tid] = tag[b * SEQ + tid];
  if (tid < 128) h_u32[tid] = 0u;
  if (tid == 0) predv[0] = 0;
  float c_reg = 0.f;
  float bout_c = (tid < 128) ? b_out[tid & 63] : 0.f;
  float loss_acc = 0.f;
  const u16* xp_row = Xp + (size_t)b * SEQ * GATES;
  ushort4 xp_c = make_ushort4(0, 0, 0, 0);
  if (tid < 256) xp_c = *(const ushort4*)(xp_row + tid * 4);
  __syncthreads();

#pragma unroll 1
  for (int s = 0; s < SEQ; ++s) {
    // ---- loop top: pred-dependent Woh + next-step Xp prefetch (hidden under A) ----
    int pred = predv[0];
    float4 woh4 = make_float4(0.f, 0.f, 0.f, 0.f);
    ushort4 xp_n = xp_c;
    if (tid < 256) {
      woh4 = Woh2[pred * 256 + tid];
      int sn = (s + 1 < SEQ) ? s + 1 : s;
      xp_n = *(const ushort4*)(xp_row + (size_t)sn * GATES + tid * 4);
    }

    // ---- phase A: partial gates matvec, K-quarter per thread ----
    float acc[8];
#pragma unroll
    for (int j = 0; j < 8; ++j) acc[j] = 0.f;
#pragma unroll
    for (int qq = 0; qq < 8; ++qq) {
      uint4 h4 = *(const uint4*)(h_u32 + kq * 32 + qq * 4);   // broadcast
      uint4 w6 = whhl[qq * 512 + tid];
      uint4 w7 = whhl[(8 + qq) * 512 + tid];
      u32 ha[4] = {h4.x, h4.y, h4.z, h4.w};
#pragma unroll
      for (int j = 0; j < 6; ++j) {
        uint4 wj = wr[j * 8 + qq];
        acc[j] = fdot2a(ha[0], wj.x, acc[j]);
        acc[j] = fdot2a(ha[1], wj.y, acc[j]);
        acc[j] = fdot2a(ha[2], wj.z, acc[j]);
        acc[j] = fdot2a(ha[3], wj.w, acc[j]);
      }
      acc[6] = fdot2a(ha[0], w6.x, acc[6]);
      acc[6] = fdot2a(ha[1], w6.y, acc[6]);
      acc[6] = fdot2a(ha[2], w6.z, acc[6]);
      acc[6] = fdot2a(ha[3], w6.w, acc[6]);
      acc[7] = fdot2a(ha[0], w7.x, acc[7]);
      acc[7] = fdot2a(ha[1], w7.y, acc[7]);
      acc[7] = fdot2a(ha[2], w7.z, acc[7]);
      acc[7] = fdot2a(ha[3], w7.w, acc[7]);
    }
#pragma unroll
    for (int j = 0; j < 8; ++j) pA[kq * 1024 + gl + j * 128] = acc[j];
    __syncthreads();

    // ---- phase B: reduce K-partials + LSTM cell (threads 0..255) ----
    if (tid < 256) {
      float ig = pA[tid]       + pA[1024 + tid] + pA[2048 + tid] + pA[3072 + tid]
               + b2f(xp_c.x) + woh4.x;
      float fg = pA[256 + tid] + pA[1280 + tid] + pA[2304 + tid] + pA[3328 + tid]
               + b2f(xp_c.y) + woh4.y;
      float gg = pA[512 + tid] + pA[1536 + tid] + pA[2560 + tid] + pA[3584 + tid]
               + b2f(xp_c.z) + woh4.z;
      float og = pA[768 + tid] + pA[1792 + tid] + pA[2816 + tid] + pA[3840 + tid]
               + b2f(xp_c.w) + woh4.w;
      float iv = sigmf_(ig), fv = sigmf_(fg), gv = tanhf_(gg), ov = sigmf_(og);
      c_reg = fv * c_reg + iv * gv;
      float h = ov * tanhf_(c_reg);
      ((u16*)h_u32)[tid] = __builtin_bit_cast(u16, (_Float16)h);
    }
    __syncthreads();

    // ---- phase C1: partial logits, thread -> (class = tid&63, kq8 = tid>>6) ----
    {
      int kq8 = tid >> 6;
      float p = 0.f;
#pragma unroll
      for (int c = 0; c < 4; ++c) {
        uint4 h4 = *(const uint4*)(h_u32 + kq8 * 16 + c * 4);
        u32 ha2[4] = {h4.x, h4.y, h4.z, h4.w};
#pragma unroll
        for (int q = 0; q < 4; ++q) p = fdot2a(ha2[q], wo[c * 4 + q], p);
      }
      pbuf[tid] = p;
    }
    __syncthreads();

    // ---- phase C2: wave0 argmax || wave1 log-softmax + NLL (parallel) ----
    if (tid < 128) {
      int cls = tid & 63;
      float lg = bout_c;
#pragma unroll
      for (int k = 0; k < 8; ++k) lg += pbuf[k * 64 + cls];
      if (tid < 64) {
        float v = lg; int ii = cls;
#pragma unroll
        for (int off = 32; off; off >>= 1) {
          float ov = __shfl_xor(v, off);
          int oi = __shfl_xor(ii, off);
          if (ov > v || (ov == v && oi < ii)) { v = ov; ii = oi; }
        }
        if (tid == 0) predv[0] = ii;
      } else {
        float v = lg;
#pragma unroll
        for (int off = 32; off; off >>= 1) v = fmaxf(v, __shfl_xor(v, off));
        float ssum = __expf(lg - v);
#pragma unroll
        for (int off = 32; off; off >>= 1) ssum += __shfl_xor(ssum, off);
        int t = tag_l[s];
        float lt = __shfl(lg, t & 63);
        if (t >= 0) loss_acc += v + __logf(ssum) - lt;
      }
    }
    xp_c = xp_n;
    __syncthreads();
  }
  if (tid == 64) atomicAdd(out, loss_acc);
}

// ---------- launcher ----------
extern "C" void kernel_launch(void* const* d_in, const int* in_sizes, int n_in,
                              void* d_out, int out_size, void* d_ws, size_t ws_size,
                              hipStream_t stream) {
  const float* x     = (const float*)d_in[0];
  const int*   tag   = (const int*)d_in[1];
  const float* W_ih  = (const float*)d_in[2];
  const float* W_hh  = (const float*)d_in[3];
  const float* b_ih  = (const float*)d_in[4];
  const float* b_hh  = (const float*)d_in[5];
  const float* W_out = (const float*)d_in[6];
  const float* b_out = (const float*)d_in[7];
  float* out = (float*)d_out;

  char* w = (char*)d_ws;
  // ws layout (bytes) — identical sizes/offsets to previous version:
  //   Xp    @ 0          : 268,435,456
  //   Wihk  @ 268435456  :   1,048,576
  //   WhhF  @ 269484032  :     393,216
  //   WhhL2 @ 269877248  :     131,072
  //   WoutR @ 270008320  :      32,768
  //   Woh2  @ 270041088  :     262,144
  u16* Xp      = (u16*)w;
  u16* Wihk    = (u16*)(w + 268435456ull);
  u32* WhhF    = (u32*)(w + 269484032ull);
  u32* WhhL2   = (u32*)(w + 269877248ull);
  u32* WoutR   = (u32*)(w + 270008320ull);
  float* Woh2  = (float*)(w + 270041088ull);

  const int smem_bytes = 38017 * 4;  // 152,068 B dynamic LDS (<=160 KB/CU)
  (void)hipFuncSetAttribute((const void*)lstm_seq,
                            hipFuncAttributeMaxDynamicSharedMemorySize, smem_bytes);

  prep_kernel<<<2849, 256, 0, stream>>>(W_ih, W_hh, W_out, Wihk, WhhF, WhhL2, WoutR, Woh2, out);
  gemm_xp<<<8192, 256, 0, stream>>>(x, Wihk, b_ih, b_hh, Xp);
  lstm_seq<<<256, 512, smem_bytes, stream>>>(Xp, (const uint4*)WhhF, (const uint4*)WhhL2,
                                             WoutR, (const float4*)Woh2, b_out, tag, out);
}